// Round 4
// baseline (130.589 us; speedup 1.0000x reference)
//
#include <hip/hip_runtime.h>

// GaussianDynamics recurrent cell as a parallel affine scan, software-pipelined.
// x_t = S_t x_{t-1} + o_t,  S_t = I + (A - xic_t C) dt,  o_t = xic_t dy_t
// out_t = C x_{t-1} dt  (pre-update state)
//
// R4: each block owns ROWS=8 consecutive batch rows and pipelines them:
//   ds_write row r (from prefetch regs) -> issue global loads for row r+1
//   -> barrier -> ds_read chunk -> compose -> wave scan -> wsum barrier
//   -> fixup/replay/stores.  Next-row HBM latency (~900 cyc) hides under
//   compose+scan (~2k cyc), converting the R3 phase-convoy (mem-time +
//   valu-time additive, 108 us) into max(mem, valu).
// Single 24.1 KB LDS buffer is reused每row: all chunk ds_reads complete
// before the wsum barrier, so next iteration's ds_writes can't race them.
// __launch_bounds__(256,4): cap 128 VGPR (base ~40 + 24 prefetch + temps).

constexpr int BATCH = 16384;
constexpr int TLEN  = 1000;
constexpr int TPB   = 256;
constexpr int SPT   = 4;               // TPB*SPT = 1024 >= TLEN
constexpr int ROWS  = 8;               // rows per block (pipeline depth)
constexpr int NBLK  = BATCH / ROWS;    // 2048 blocks

typedef float vfloat4 __attribute__((ext_vector_type(4)));
typedef float vfloat2 __attribute__((ext_vector_type(2)));

__global__ __launch_bounds__(TPB, 4) void gd_scan_kernel(
    const float* __restrict__ xicovs,  // [B,T,2,2]
    const float* __restrict__ dyv,     // [B,T,2]
    const float* __restrict__ cA,      // [2,2]
    const float* __restrict__ Cm,      // [2,2]
    const float* __restrict__ x0,      // [B,2]
    const float* __restrict__ dtp,     // [1]
    float* __restrict__ out)           // [B,T,2] then [B,2]
{
    __shared__ float s_xi00[TLEN], s_xi01[TLEN], s_xi10[TLEN], s_xi11[TLEN];
    __shared__ float s_dy0[TLEN],  s_dy1[TLEN];
    __shared__ float wsum[TPB / 64][6];

    const int tid  = threadIdx.x;
    const int lane = tid & 63;
    const int wv   = tid >> 6;
    const int row0 = blockIdx.x * ROWS;

    const float dts = dtp[0];
    const float C00 = Cm[0], C01 = Cm[1], C10 = Cm[2], C11 = Cm[3];
    const float A00 = cA[0], A01 = cA[1], A10 = cA[2], A11 = cA[3];

    const int t0  = tid * SPT;                                  // logical chunk start
    const int t0m = (t0 <= TLEN - SPT) ? t0 : (TLEN - SPT);     // clamped LDS read addr

    vfloat4 pf_x[4];   // prefetched xicov elements (row r+1 in steady state)
    vfloat2 pf_d[4];

    // ---- prologue: prefetch row0 ----
    {
        const vfloat4* gx = reinterpret_cast<const vfloat4*>(xicovs + (size_t)row0 * TLEN * 4);
        const vfloat2* gd = reinterpret_cast<const vfloat2*>(dyv    + (size_t)row0 * TLEN * 2);
#pragma unroll
        for (int k = 0; k < 4; ++k) {
            int i = tid + k * TPB; if (i >= TLEN) i = TLEN - 1;
            pf_x[k] = gx[i];
            pf_d[k] = gd[i];
        }
    }

    for (int r = 0; r < ROWS; ++r) {
        const int row = row0 + r;

        // ---- stage current row into LDS (SoA transpose), conflict-free ----
#pragma unroll
        for (int k = 0; k < 4; ++k) {
            const int i = tid + k * TPB;
            if (i < TLEN) {
                s_xi00[i] = pf_x[k].x; s_xi01[i] = pf_x[k].y;
                s_xi10[i] = pf_x[k].z; s_xi11[i] = pf_x[k].w;
                s_dy0[i]  = pf_d[k].x; s_dy1[i]  = pf_d[k].y;
            }
        }

        // ---- issue next row's global loads; they fly under compose+scan ----
        if (r + 1 < ROWS) {
            const vfloat4* gx = reinterpret_cast<const vfloat4*>(xicovs + (size_t)(row + 1) * TLEN * 4);
            const vfloat2* gd = reinterpret_cast<const vfloat2*>(dyv    + (size_t)(row + 1) * TLEN * 2);
#pragma unroll
            for (int k = 0; k < 4; ++k) {
                int i = tid + k * TPB; if (i >= TLEN) i = TLEN - 1;
                pf_x[k] = gx[i];
                pf_d[k] = gd[i];
            }
        }

        __syncthreads();   // barrier A: staging visible

        // ---- chunk read: contiguous SoA ds_read_b128 ----
        const vfloat4 q00 = *reinterpret_cast<const vfloat4*>(&s_xi00[t0m]);
        const vfloat4 q01 = *reinterpret_cast<const vfloat4*>(&s_xi01[t0m]);
        const vfloat4 q10 = *reinterpret_cast<const vfloat4*>(&s_xi10[t0m]);
        const vfloat4 q11 = *reinterpret_cast<const vfloat4*>(&s_xi11[t0m]);
        const vfloat4 qd0 = *reinterpret_cast<const vfloat4*>(&s_dy0[t0m]);
        const vfloat4 qd1 = *reinterpret_cast<const vfloat4*>(&s_dy1[t0m]);

        const float xi00s[SPT] = {q00.x, q00.y, q00.z, q00.w};
        const float xi01s[SPT] = {q01.x, q01.y, q01.z, q01.w};
        const float xi10s[SPT] = {q10.x, q10.y, q10.z, q10.w};
        const float xi11s[SPT] = {q11.x, q11.y, q11.z, q11.w};
        const float dy0s[SPT]  = {qd0.x, qd0.y, qd0.z, qd0.w};
        const float dy1s[SPT]  = {qd1.x, qd1.y, qd1.z, qd1.w};

        // ---- per-step affine (S,o), composed in time order ----
        float S00s[SPT], S01s[SPT], S10s[SPT], S11s[SPT], o0s[SPT], o1s[SPT];
        float M00 = 1.f, M01 = 0.f, M10 = 0.f, M11 = 1.f, c0 = 0.f, c1 = 0.f;
#pragma unroll
        for (int s = 0; s < SPT; ++s) {
            const int t = t0 + s;
            const float xi00 = xi00s[s], xi01 = xi01s[s], xi10 = xi10s[s], xi11 = xi11s[s];
            const float Am00 = A00 - (xi00 * C00 + xi01 * C10);
            const float Am01 = A01 - (xi00 * C01 + xi01 * C11);
            const float Am10 = A10 - (xi10 * C00 + xi11 * C10);
            const float Am11 = A11 - (xi10 * C01 + xi11 * C11);
            float S00 = 1.f + Am00 * dts, S01 = Am01 * dts;
            float S10 = Am10 * dts,       S11 = 1.f + Am11 * dts;
            float o0 = xi00 * dy0s[s] + xi01 * dy1s[s];
            float o1 = xi10 * dy0s[s] + xi11 * dy1s[s];
            if (t >= TLEN) { S00 = 1.f; S01 = 0.f; S10 = 0.f; S11 = 1.f; o0 = 0.f; o1 = 0.f; }
            S00s[s] = S00; S01s[s] = S01; S10s[s] = S10; S11s[s] = S11; o0s[s] = o0; o1s[s] = o1;
            const float n00 = S00 * M00 + S01 * M10;
            const float n01 = S00 * M01 + S01 * M11;
            const float n10 = S10 * M00 + S11 * M10;
            const float n11 = S10 * M01 + S11 * M11;
            const float nc0 = S00 * c0 + S01 * c1 + o0;
            const float nc1 = S10 * c0 + S11 * c1 + o1;
            M00 = n00; M01 = n01; M10 = n10; M11 = n11; c0 = nc0; c1 = nc1;
        }

        // ---- wave-level inclusive scan (Hillis-Steele over 64 lanes) ----
#pragma unroll
        for (int off = 1; off < 64; off <<= 1) {
            const float m00 = __shfl_up(M00, off);
            const float m01 = __shfl_up(M01, off);
            const float m10 = __shfl_up(M10, off);
            const float m11 = __shfl_up(M11, off);
            const float lc0 = __shfl_up(c0,  off);
            const float lc1 = __shfl_up(c1,  off);
            if (lane >= off) {
                const float n00 = M00 * m00 + M01 * m10;
                const float n01 = M00 * m01 + M01 * m11;
                const float n10 = M10 * m00 + M11 * m10;
                const float n11 = M10 * m01 + M11 * m11;
                const float nc0 = M00 * lc0 + M01 * lc1 + c0;
                const float nc1 = M10 * lc0 + M11 * lc1 + c1;
                M00 = n00; M01 = n01; M10 = n10; M11 = n11; c0 = nc0; c1 = nc1;
            }
        }

        // ---- inter-wave fixup ----
        if (lane == 63) {
            wsum[wv][0] = M00; wsum[wv][1] = M01; wsum[wv][2] = M10; wsum[wv][3] = M11;
            wsum[wv][4] = c0;  wsum[wv][5] = c1;
        }
        __syncthreads();   // barrier B: wsum visible (also fences chunk reads)

        float P00 = 1.f, P01 = 0.f, P10 = 0.f, P11 = 1.f, Pc0 = 0.f, Pc1 = 0.f;
        for (int w = 0; w < wv; ++w) {
            const float w00 = wsum[w][0], w01 = wsum[w][1], w10 = wsum[w][2], w11 = wsum[w][3];
            const float wc0 = wsum[w][4], wc1 = wsum[w][5];
            const float n00 = w00 * P00 + w01 * P10;
            const float n01 = w00 * P01 + w01 * P11;
            const float n10 = w10 * P00 + w11 * P10;
            const float n11 = w10 * P01 + w11 * P11;
            const float nc0 = w00 * Pc0 + w01 * Pc1 + wc0;
            const float nc1 = w10 * Pc0 + w11 * Pc1 + wc1;
            P00 = n00; P01 = n01; P10 = n10; P11 = n11; Pc0 = nc0; Pc1 = nc1;
        }

        // ---- within-wave exclusive = inclusive of lane-1 ----
        float e00 = __shfl_up(M00, 1), e01 = __shfl_up(M01, 1);
        float e10 = __shfl_up(M10, 1), e11 = __shfl_up(M11, 1);
        float ec0 = __shfl_up(c0, 1),  ec1 = __shfl_up(c1, 1);
        if (lane == 0) { e00 = 1.f; e01 = 0.f; e10 = 0.f; e11 = 1.f; ec0 = 0.f; ec1 = 0.f; }

        const float E00 = e00 * P00 + e01 * P10;
        const float E01 = e00 * P01 + e01 * P11;
        const float E10 = e10 * P00 + e11 * P10;
        const float E11 = e10 * P01 + e11 * P11;
        const float Ec0 = e00 * Pc0 + e01 * Pc1 + ec0;
        const float Ec1 = e10 * Pc0 + e11 * Pc1 + ec1;

        // start state for this chunk: x_{t0-1} = E(x0)
        const float xa = x0[2 * row], xb = x0[2 * row + 1];
        float xq0 = E00 * xa + E01 * xb + Ec0;
        float xq1 = E10 * xa + E11 * xb + Ec1;

        // ---- replay chunk from registers, emit outputs ----
        float o0v[SPT], o1v[SPT];
#pragma unroll
        for (int s = 0; s < SPT; ++s) {
            o0v[s] = (C00 * xq0 + C01 * xq1) * dts;
            o1v[s] = (C10 * xq0 + C11 * xq1) * dts;
            const float nx0 = S00s[s] * xq0 + S01s[s] * xq1 + o0s[s];
            const float nx1 = S10s[s] * xq0 + S11s[s] * xq1 + o1s[s];
            xq0 = nx0; xq1 = nx1;
        }

        float* ob = out + (size_t)row * TLEN * 2 + (size_t)t0 * 2;
        if (t0 + SPT <= TLEN) {
            vfloat4 w0 = {o0v[0], o1v[0], o0v[1], o1v[1]};
            vfloat4 w1 = {o0v[2], o1v[2], o0v[3], o1v[3]};
            __builtin_nontemporal_store(w0, reinterpret_cast<vfloat4*>(ob));
            __builtin_nontemporal_store(w1, reinterpret_cast<vfloat4*>(ob) + 1);
        } else {
            for (int s = 0; s < SPT; ++s)
                if (t0 + s < TLEN) {
                    vfloat2 w = {o0v[s], o1v[s]};
                    __builtin_nontemporal_store(w, reinterpret_cast<vfloat2*>(ob) + s);
                }
        }

        // thread owning the last timestep writes the final state
        if (t0 < TLEN && t0 + SPT >= TLEN) {
            float* xf = out + (size_t)BATCH * TLEN * 2 + 2 * row;
            xf[0] = xq0; xf[1] = xq1;
        }
    }
}

extern "C" void kernel_launch(void* const* d_in, const int* in_sizes, int n_in,
                              void* d_out, int out_size, void* d_ws, size_t ws_size,
                              hipStream_t stream) {
    const float* xicovs = (const float*)d_in[0];
    const float* dyv    = (const float*)d_in[1];
    const float* cA     = (const float*)d_in[2];
    const float* Cm     = (const float*)d_in[3];
    const float* x0     = (const float*)d_in[4];
    const float* dtp    = (const float*)d_in[5];
    float* out = (float*)d_out;

    gd_scan_kernel<<<NBLK, TPB, 0, stream>>>(xicovs, dyv, cA, Cm, x0, dtp, out);
}

// Round 5
// 103.312 us; speedup vs baseline: 1.2640x; 1.2640x over previous
//
#include <hip/hip_runtime.h>

// GaussianDynamics recurrent cell as a parallel affine scan.
// x_t = S_t x_{t-1} + o_t,  S_t = I + (A - xic_t C) dt,  o_t = xic_t dy_t
// out_t = C x_{t-1} dt  (pre-update state)
//
// R5 = R3 (108us) with the wave scan's 36 ds_bpermute (__shfl_up) replaced by
// DPP register shuffles (row_shr:1/2/4/8 + row_bcast:15 + row_bcast:31),
// passing the affine IDENTITY as update_dpp's `old` so invalid/masked lanes
// compose with identity (guard-free Hillis-Steele). Moves the scan off the
// shared LDS pipe onto VALU and shortens the dependent chain.
// R4's row-loop pipeline REVERTED (it cut occupancy 64->40% and regressed).

constexpr int BATCH = 16384;
constexpr int TLEN  = 1000;
constexpr int TPB   = 256;
constexpr int SPT   = 4;     // TPB*SPT = 1024 >= TLEN
constexpr int TPAD  = 1024;

typedef float vfloat4 __attribute__((ext_vector_type(4)));
typedef float vfloat2 __attribute__((ext_vector_type(2)));

// DPP move: result = shifted src; lanes with no valid source (or rows masked
// off) receive `oldv`. bound_ctrl=false => invalid lanes keep old.
template <int CTRL, int ROWMASK>
__device__ __forceinline__ float dppf(float oldv, float srcv) {
    return __int_as_float(__builtin_amdgcn_update_dpp(
        __float_as_int(oldv), __float_as_int(srcv), CTRL, ROWMASK, 0xf, false));
}

__global__ __launch_bounds__(TPB, 6) void gd_scan_kernel(
    const float* __restrict__ xicovs,  // [B,T,2,2]
    const float* __restrict__ dyv,     // [B,T,2]
    const float* __restrict__ cA,      // [2,2]
    const float* __restrict__ Cm,      // [2,2]
    const float* __restrict__ x0,      // [B,2]
    const float* __restrict__ dtp,     // [1]
    float* __restrict__ out)           // [B,T,2] then [B,2]
{
    __shared__ float s_xi00[TPAD], s_xi01[TPAD], s_xi10[TPAD], s_xi11[TPAD];
    __shared__ float s_dy0[TPAD], s_dy1[TPAD];
    __shared__ float wsum[TPB / 64][6];

    const int b    = blockIdx.x;
    const int tid  = threadIdx.x;
    const int lane = tid & 63;
    const int wv   = tid >> 6;

    // ---- stage row into LDS, SoA transpose, fully coalesced global loads ----
    {
        const vfloat4* gx = reinterpret_cast<const vfloat4*>(xicovs + (size_t)b * TLEN * 4);
        for (int i = tid; i < TLEN; i += TPB) {
            const vfloat4 v = gx[i];
            s_xi00[i] = v.x; s_xi01[i] = v.y; s_xi10[i] = v.z; s_xi11[i] = v.w;
        }
        const vfloat2* gd = reinterpret_cast<const vfloat2*>(dyv + (size_t)b * TLEN * 2);
        for (int i = tid; i < TLEN; i += TPB) {
            const vfloat2 v = gd[i];
            s_dy0[i] = v.x; s_dy1[i] = v.y;
        }
    }

    const float dts = dtp[0];
    const float C00 = Cm[0], C01 = Cm[1], C10 = Cm[2], C11 = Cm[3];
    const float A00 = cA[0], A01 = cA[1], A10 = cA[2], A11 = cA[3];

    __syncthreads();

    const int t0 = tid * SPT;

    // ---- read this thread's 4 steps: contiguous 16B LDS reads, SoA ----
    const vfloat4 q00 = *reinterpret_cast<const vfloat4*>(&s_xi00[t0]);
    const vfloat4 q01 = *reinterpret_cast<const vfloat4*>(&s_xi01[t0]);
    const vfloat4 q10 = *reinterpret_cast<const vfloat4*>(&s_xi10[t0]);
    const vfloat4 q11 = *reinterpret_cast<const vfloat4*>(&s_xi11[t0]);
    const vfloat4 qd0 = *reinterpret_cast<const vfloat4*>(&s_dy0[t0]);
    const vfloat4 qd1 = *reinterpret_cast<const vfloat4*>(&s_dy1[t0]);

    const float xi00s[SPT] = {q00.x, q00.y, q00.z, q00.w};
    const float xi01s[SPT] = {q01.x, q01.y, q01.z, q01.w};
    const float xi10s[SPT] = {q10.x, q10.y, q10.z, q10.w};
    const float xi11s[SPT] = {q11.x, q11.y, q11.z, q11.w};
    const float dy0s[SPT]  = {qd0.x, qd0.y, qd0.z, qd0.w};
    const float dy1s[SPT]  = {qd1.x, qd1.y, qd1.z, qd1.w};

    // ---- per-step affine (S,o), composed in time order ----
    float S00s[SPT], S01s[SPT], S10s[SPT], S11s[SPT], o0s[SPT], o1s[SPT];
    float M00 = 1.f, M01 = 0.f, M10 = 0.f, M11 = 1.f, c0 = 0.f, c1 = 0.f;
#pragma unroll
    for (int s = 0; s < SPT; ++s) {
        const int t = t0 + s;
        const float xi00 = xi00s[s], xi01 = xi01s[s], xi10 = xi10s[s], xi11 = xi11s[s];
        const float Am00 = A00 - (xi00 * C00 + xi01 * C10);
        const float Am01 = A01 - (xi00 * C01 + xi01 * C11);
        const float Am10 = A10 - (xi10 * C00 + xi11 * C10);
        const float Am11 = A11 - (xi10 * C01 + xi11 * C11);
        float S00 = 1.f + Am00 * dts, S01 = Am01 * dts;
        float S10 = Am10 * dts,       S11 = 1.f + Am11 * dts;
        float o0 = xi00 * dy0s[s] + xi01 * dy1s[s];
        float o1 = xi10 * dy0s[s] + xi11 * dy1s[s];
        if (t >= TLEN) { S00 = 1.f; S01 = 0.f; S10 = 0.f; S11 = 1.f; o0 = 0.f; o1 = 0.f; }
        S00s[s] = S00; S01s[s] = S01; S10s[s] = S10; S11s[s] = S11; o0s[s] = o0; o1s[s] = o1;
        const float n00 = S00 * M00 + S01 * M10;
        const float n01 = S00 * M01 + S01 * M11;
        const float n10 = S10 * M00 + S11 * M10;
        const float n11 = S10 * M01 + S11 * M11;
        const float nc0 = S00 * c0 + S01 * c1 + o0;
        const float nc1 = S10 * c0 + S11 * c1 + o1;
        M00 = n00; M01 = n01; M10 = n10; M11 = n11; c0 = nc0; c1 = nc1;
    }

    // ---- wave-level inclusive scan via DPP (VALU, no LDS pipe) ----
    // new = cur o shifted : M = M_cur*m_sh ; c = M_cur*c_sh + c_cur.
    // Invalid/masked lanes receive identity (I,0) => compose is a no-op.
#define SCAN_STEP(CTRL, RM)                                        \
    do {                                                           \
        const float m00 = dppf<CTRL, RM>(1.f, M00);                \
        const float m01 = dppf<CTRL, RM>(0.f, M01);                \
        const float m10 = dppf<CTRL, RM>(0.f, M10);                \
        const float m11 = dppf<CTRL, RM>(1.f, M11);                \
        const float lc0 = dppf<CTRL, RM>(0.f, c0);                 \
        const float lc1 = dppf<CTRL, RM>(0.f, c1);                 \
        const float n00 = M00 * m00 + M01 * m10;                   \
        const float n01 = M00 * m01 + M01 * m11;                   \
        const float n10 = M10 * m00 + M11 * m10;                   \
        const float n11 = M10 * m01 + M11 * m11;                   \
        const float nc0 = M00 * lc0 + M01 * lc1 + c0;              \
        const float nc1 = M10 * lc0 + M11 * lc1 + c1;              \
        M00 = n00; M01 = n01; M10 = n10; M11 = n11;                \
        c0 = nc0; c1 = nc1;                                        \
    } while (0)

    SCAN_STEP(0x111, 0xf);  // row_shr:1
    SCAN_STEP(0x112, 0xf);  // row_shr:2
    SCAN_STEP(0x114, 0xf);  // row_shr:4
    SCAN_STEP(0x118, 0xf);  // row_shr:8
    SCAN_STEP(0x142, 0xa);  // row_bcast:15 -> rows 1,3
    SCAN_STEP(0x143, 0xc);  // row_bcast:31 -> rows 2,3
#undef SCAN_STEP

    // ---- inter-wave fixup ----
    if (lane == 63) {
        wsum[wv][0] = M00; wsum[wv][1] = M01; wsum[wv][2] = M10; wsum[wv][3] = M11;
        wsum[wv][4] = c0;  wsum[wv][5] = c1;
    }
    __syncthreads();

    float P00 = 1.f, P01 = 0.f, P10 = 0.f, P11 = 1.f, Pc0 = 0.f, Pc1 = 0.f;
    for (int w = 0; w < wv; ++w) {
        const float w00 = wsum[w][0], w01 = wsum[w][1], w10 = wsum[w][2], w11 = wsum[w][3];
        const float wc0 = wsum[w][4], wc1 = wsum[w][5];
        const float n00 = w00 * P00 + w01 * P10;
        const float n01 = w00 * P01 + w01 * P11;
        const float n10 = w10 * P00 + w11 * P10;
        const float n11 = w10 * P01 + w11 * P11;
        const float nc0 = w00 * Pc0 + w01 * Pc1 + wc0;
        const float nc1 = w10 * Pc0 + w11 * Pc1 + wc1;
        P00 = n00; P01 = n01; P10 = n10; P11 = n11; Pc0 = nc0; Pc1 = nc1;
    }

    // ---- within-wave exclusive = inclusive of lane-1 (crosses DPP rows:
    //      keep __shfl_up here) ----
    float e00 = __shfl_up(M00, 1), e01 = __shfl_up(M01, 1);
    float e10 = __shfl_up(M10, 1), e11 = __shfl_up(M11, 1);
    float ec0 = __shfl_up(c0, 1),  ec1 = __shfl_up(c1, 1);
    if (lane == 0) { e00 = 1.f; e01 = 0.f; e10 = 0.f; e11 = 1.f; ec0 = 0.f; ec1 = 0.f; }

    // E = e o P
    const float E00 = e00 * P00 + e01 * P10;
    const float E01 = e00 * P01 + e01 * P11;
    const float E10 = e10 * P00 + e11 * P10;
    const float E11 = e10 * P01 + e11 * P11;
    const float Ec0 = e00 * Pc0 + e01 * Pc1 + ec0;
    const float Ec1 = e10 * Pc0 + e11 * Pc1 + ec1;

    // start state for this chunk: x_{t0-1} = E(x0)
    const float xa = x0[2 * b], xb = x0[2 * b + 1];
    float xq0 = E00 * xa + E01 * xb + Ec0;
    float xq1 = E10 * xa + E11 * xb + Ec1;

    // ---- replay chunk from (S,o) in registers, emit outputs ----
    float o0v[SPT], o1v[SPT];
#pragma unroll
    for (int s = 0; s < SPT; ++s) {
        o0v[s] = (C00 * xq0 + C01 * xq1) * dts;
        o1v[s] = (C10 * xq0 + C11 * xq1) * dts;
        const float nx0 = S00s[s] * xq0 + S01s[s] * xq1 + o0s[s];
        const float nx1 = S10s[s] * xq0 + S11s[s] * xq1 + o1s[s];
        xq0 = nx0; xq1 = nx1;
    }

    float* ob = out + (size_t)b * TLEN * 2 + (size_t)t0 * 2;
    if (t0 + SPT <= TLEN) {
        vfloat4 w0 = {o0v[0], o1v[0], o0v[1], o1v[1]};
        vfloat4 w1 = {o0v[2], o1v[2], o0v[3], o1v[3]};
        __builtin_nontemporal_store(w0, reinterpret_cast<vfloat4*>(ob));
        __builtin_nontemporal_store(w1, reinterpret_cast<vfloat4*>(ob) + 1);
    } else {
        for (int s = 0; s < SPT; ++s)
            if (t0 + s < TLEN) {
                vfloat2 w = {o0v[s], o1v[s]};
                __builtin_nontemporal_store(w, reinterpret_cast<vfloat2*>(ob) + s);
            }
    }

    // thread owning the last timestep writes the final state
    if (t0 < TLEN && t0 + SPT >= TLEN) {
        float* xf = out + (size_t)BATCH * TLEN * 2 + 2 * b;
        xf[0] = xq0; xf[1] = xq1;
    }
}

extern "C" void kernel_launch(void* const* d_in, const int* in_sizes, int n_in,
                              void* d_out, int out_size, void* d_ws, size_t ws_size,
                              hipStream_t stream) {
    const float* xicovs = (const float*)d_in[0];
    const float* dyv    = (const float*)d_in[1];
    const float* cA     = (const float*)d_in[2];
    const float* Cm     = (const float*)d_in[3];
    const float* x0     = (const float*)d_in[4];
    const float* dtp    = (const float*)d_in[5];
    float* out = (float*)d_out;

    gd_scan_kernel<<<BATCH, TPB, 0, stream>>>(xicovs, dyv, cA, Cm, x0, dtp, out);
}

// Round 6
// 100.390 us; speedup vs baseline: 1.3008x; 1.0291x over previous
//
#include <hip/hip_runtime.h>

// GaussianDynamics recurrent cell as a parallel affine scan.
// x_t = S_t x_{t-1} + o_t,  S_t = I + (A - xic_t C) dt,  o_t = xic_t dy_t
// out_t = C x_{t-1} dt  (pre-update state)
//
// R6 = R5 (103us) with LDS cut 25KB -> 15.7KB: only xicov is staged/transposed
// through LDS; dy is loaded directly per-thread (32 contiguous bytes = 2x
// dwordx4, issued before staging so latency hides under the barrier). This
// lifts the LDS block-residency cap 6 -> 8 blocks/CU (32-wave ceiling), giving
// more phase-staggered blocks to overlap memory and VALU phases (R5 counters:
// both pipes ~50% => overlap-limited, not pipe-limited).
// Scan stays DPP (row_shr/row_bcast with identity fill), R5-verified.

constexpr int BATCH = 16384;
constexpr int TLEN  = 1000;
constexpr int TPB   = 256;
constexpr int SPT   = 4;     // TPB*SPT = 1024 >= TLEN

typedef float vfloat4 __attribute__((ext_vector_type(4)));
typedef float vfloat2 __attribute__((ext_vector_type(2)));

template <int CTRL, int ROWMASK>
__device__ __forceinline__ float dppf(float oldv, float srcv) {
    return __int_as_float(__builtin_amdgcn_update_dpp(
        __float_as_int(oldv), __float_as_int(srcv), CTRL, ROWMASK, 0xf, false));
}

__global__ __launch_bounds__(TPB, 8) void gd_scan_kernel(
    const float* __restrict__ xicovs,  // [B,T,2,2]
    const float* __restrict__ dyv,     // [B,T,2]
    const float* __restrict__ cA,      // [2,2]
    const float* __restrict__ Cm,      // [2,2]
    const float* __restrict__ x0,      // [B,2]
    const float* __restrict__ dtp,     // [1]
    float* __restrict__ out)           // [B,T,2] then [B,2]
{
    __shared__ float s_xi00[TLEN], s_xi01[TLEN], s_xi10[TLEN], s_xi11[TLEN];
    __shared__ float wsum[TPB / 64][6];

    const int b    = blockIdx.x;
    const int tid  = threadIdx.x;
    const int lane = tid & 63;
    const int wv   = tid >> 6;

    const int t0  = tid * SPT;
    const int t0m = (t0 <= TLEN - SPT) ? t0 : (TLEN - SPT);  // clamped chunk base

    // ---- issue dy loads FIRST (per-thread contiguous 32B, 16B-aligned);
    //      latency hides under xicov staging + barrier ----
    const vfloat4* gd4 = reinterpret_cast<const vfloat4*>(dyv + (size_t)b * TLEN * 2);
    const int di = 2 * ((t0m < 0) ? 0 : (t0m >> 1) * (SPT >> 1) / (SPT >> 1));  // = 2*(t0m/2)
    const vfloat4 dA = gd4[(t0m >> 1)];      // dy0[t0m],dy1[t0m],dy0[t0m+1],dy1[t0m+1]
    const vfloat4 dB = gd4[(t0m >> 1) + 1];  // next two steps
    (void)di;

    // ---- stage xicov into LDS (SoA transpose), fully coalesced ----
    {
        const vfloat4* gx = reinterpret_cast<const vfloat4*>(xicovs + (size_t)b * TLEN * 4);
        for (int i = tid; i < TLEN; i += TPB) {
            const vfloat4 v = gx[i];
            s_xi00[i] = v.x; s_xi01[i] = v.y; s_xi10[i] = v.z; s_xi11[i] = v.w;
        }
    }

    const float dts = dtp[0];
    const float C00 = Cm[0], C01 = Cm[1], C10 = Cm[2], C11 = Cm[3];
    const float A00 = cA[0], A01 = cA[1], A10 = cA[2], A11 = cA[3];

    __syncthreads();

    // ---- chunk read: contiguous SoA ds_read_b128 ----
    const vfloat4 q00 = *reinterpret_cast<const vfloat4*>(&s_xi00[t0m]);
    const vfloat4 q01 = *reinterpret_cast<const vfloat4*>(&s_xi01[t0m]);
    const vfloat4 q10 = *reinterpret_cast<const vfloat4*>(&s_xi10[t0m]);
    const vfloat4 q11 = *reinterpret_cast<const vfloat4*>(&s_xi11[t0m]);

    const float xi00s[SPT] = {q00.x, q00.y, q00.z, q00.w};
    const float xi01s[SPT] = {q01.x, q01.y, q01.z, q01.w};
    const float xi10s[SPT] = {q10.x, q10.y, q10.z, q10.w};
    const float xi11s[SPT] = {q11.x, q11.y, q11.z, q11.w};
    const float dy0s[SPT]  = {dA.x, dA.z, dB.x, dB.z};
    const float dy1s[SPT]  = {dA.y, dA.w, dB.y, dB.w};

    // ---- per-step affine (S,o), composed in time order ----
    float S00s[SPT], S01s[SPT], S10s[SPT], S11s[SPT], o0s[SPT], o1s[SPT];
    float M00 = 1.f, M01 = 0.f, M10 = 0.f, M11 = 1.f, c0 = 0.f, c1 = 0.f;
#pragma unroll
    for (int s = 0; s < SPT; ++s) {
        const int t = t0 + s;   // logical time (t0, not t0m) drives the guard
        const float xi00 = xi00s[s], xi01 = xi01s[s], xi10 = xi10s[s], xi11 = xi11s[s];
        const float Am00 = A00 - (xi00 * C00 + xi01 * C10);
        const float Am01 = A01 - (xi00 * C01 + xi01 * C11);
        const float Am10 = A10 - (xi10 * C00 + xi11 * C10);
        const float Am11 = A11 - (xi10 * C01 + xi11 * C11);
        float S00 = 1.f + Am00 * dts, S01 = Am01 * dts;
        float S10 = Am10 * dts,       S11 = 1.f + Am11 * dts;
        float o0 = xi00 * dy0s[s] + xi01 * dy1s[s];
        float o1 = xi10 * dy0s[s] + xi11 * dy1s[s];
        if (t >= TLEN) { S00 = 1.f; S01 = 0.f; S10 = 0.f; S11 = 1.f; o0 = 0.f; o1 = 0.f; }
        S00s[s] = S00; S01s[s] = S01; S10s[s] = S10; S11s[s] = S11; o0s[s] = o0; o1s[s] = o1;
        const float n00 = S00 * M00 + S01 * M10;
        const float n01 = S00 * M01 + S01 * M11;
        const float n10 = S10 * M00 + S11 * M10;
        const float n11 = S10 * M01 + S11 * M11;
        const float nc0 = S00 * c0 + S01 * c1 + o0;
        const float nc1 = S10 * c0 + S11 * c1 + o1;
        M00 = n00; M01 = n01; M10 = n10; M11 = n11; c0 = nc0; c1 = nc1;
    }

    // ---- wave-level inclusive scan via DPP (VALU, no LDS pipe) ----
#define SCAN_STEP(CTRL, RM)                                        \
    do {                                                           \
        const float m00 = dppf<CTRL, RM>(1.f, M00);                \
        const float m01 = dppf<CTRL, RM>(0.f, M01);                \
        const float m10 = dppf<CTRL, RM>(0.f, M10);                \
        const float m11 = dppf<CTRL, RM>(1.f, M11);                \
        const float lc0 = dppf<CTRL, RM>(0.f, c0);                 \
        const float lc1 = dppf<CTRL, RM>(0.f, c1);                 \
        const float n00 = M00 * m00 + M01 * m10;                   \
        const float n01 = M00 * m01 + M01 * m11;                   \
        const float n10 = M10 * m00 + M11 * m10;                   \
        const float n11 = M10 * m01 + M11 * m11;                   \
        const float nc0 = M00 * lc0 + M01 * lc1 + c0;              \
        const float nc1 = M10 * lc0 + M11 * lc1 + c1;              \
        M00 = n00; M01 = n01; M10 = n10; M11 = n11;                \
        c0 = nc0; c1 = nc1;                                        \
    } while (0)

    SCAN_STEP(0x111, 0xf);  // row_shr:1
    SCAN_STEP(0x112, 0xf);  // row_shr:2
    SCAN_STEP(0x114, 0xf);  // row_shr:4
    SCAN_STEP(0x118, 0xf);  // row_shr:8
    SCAN_STEP(0x142, 0xa);  // row_bcast:15 -> rows 1,3
    SCAN_STEP(0x143, 0xc);  // row_bcast:31 -> rows 2,3
#undef SCAN_STEP

    // ---- inter-wave fixup ----
    if (lane == 63) {
        wsum[wv][0] = M00; wsum[wv][1] = M01; wsum[wv][2] = M10; wsum[wv][3] = M11;
        wsum[wv][4] = c0;  wsum[wv][5] = c1;
    }
    __syncthreads();

    float P00 = 1.f, P01 = 0.f, P10 = 0.f, P11 = 1.f, Pc0 = 0.f, Pc1 = 0.f;
    for (int w = 0; w < wv; ++w) {
        const float w00 = wsum[w][0], w01 = wsum[w][1], w10 = wsum[w][2], w11 = wsum[w][3];
        const float wc0 = wsum[w][4], wc1 = wsum[w][5];
        const float n00 = w00 * P00 + w01 * P10;
        const float n01 = w00 * P01 + w01 * P11;
        const float n10 = w10 * P00 + w11 * P10;
        const float n11 = w10 * P01 + w11 * P11;
        const float nc0 = w00 * Pc0 + w01 * Pc1 + wc0;
        const float nc1 = w10 * Pc0 + w11 * Pc1 + wc1;
        P00 = n00; P01 = n01; P10 = n10; P11 = n11; Pc0 = nc0; Pc1 = nc1;
    }

    // ---- within-wave exclusive = inclusive of lane-1 ----
    float e00 = __shfl_up(M00, 1), e01 = __shfl_up(M01, 1);
    float e10 = __shfl_up(M10, 1), e11 = __shfl_up(M11, 1);
    float ec0 = __shfl_up(c0, 1),  ec1 = __shfl_up(c1, 1);
    if (lane == 0) { e00 = 1.f; e01 = 0.f; e10 = 0.f; e11 = 1.f; ec0 = 0.f; ec1 = 0.f; }

    // E = e o P
    const float E00 = e00 * P00 + e01 * P10;
    const float E01 = e00 * P01 + e01 * P11;
    const float E10 = e10 * P00 + e11 * P10;
    const float E11 = e10 * P01 + e11 * P11;
    const float Ec0 = e00 * Pc0 + e01 * Pc1 + ec0;
    const float Ec1 = e10 * Pc0 + e11 * Pc1 + ec1;

    // start state for this chunk: x_{t0-1} = E(x0)
    const float xa = x0[2 * b], xb = x0[2 * b + 1];
    float xq0 = E00 * xa + E01 * xb + Ec0;
    float xq1 = E10 * xa + E11 * xb + Ec1;

    // ---- replay chunk from (S,o) in registers, emit outputs ----
    float o0v[SPT], o1v[SPT];
#pragma unroll
    for (int s = 0; s < SPT; ++s) {
        o0v[s] = (C00 * xq0 + C01 * xq1) * dts;
        o1v[s] = (C10 * xq0 + C11 * xq1) * dts;
        const float nx0 = S00s[s] * xq0 + S01s[s] * xq1 + o0s[s];
        const float nx1 = S10s[s] * xq0 + S11s[s] * xq1 + o1s[s];
        xq0 = nx0; xq1 = nx1;
    }

    float* ob = out + (size_t)b * TLEN * 2 + (size_t)t0 * 2;
    if (t0 + SPT <= TLEN) {
        vfloat4 w0 = {o0v[0], o1v[0], o0v[1], o1v[1]};
        vfloat4 w1 = {o0v[2], o1v[2], o0v[3], o1v[3]};
        __builtin_nontemporal_store(w0, reinterpret_cast<vfloat4*>(ob));
        __builtin_nontemporal_store(w1, reinterpret_cast<vfloat4*>(ob) + 1);
    } else {
        for (int s = 0; s < SPT; ++s)
            if (t0 + s < TLEN) {
                vfloat2 w = {o0v[s], o1v[s]};
                __builtin_nontemporal_store(w, reinterpret_cast<vfloat2*>(ob) + s);
            }
    }

    // thread owning the last timestep writes the final state
    if (t0 < TLEN && t0 + SPT >= TLEN) {
        float* xf = out + (size_t)BATCH * TLEN * 2 + 2 * b;
        xf[0] = xq0; xf[1] = xq1;
    }
}

extern "C" void kernel_launch(void* const* d_in, const int* in_sizes, int n_in,
                              void* d_out, int out_size, void* d_ws, size_t ws_size,
                              hipStream_t stream) {
    const float* xicovs = (const float*)d_in[0];
    const float* dyv    = (const float*)d_in[1];
    const float* cA     = (const float*)d_in[2];
    const float* Cm     = (const float*)d_in[3];
    const float* x0     = (const float*)d_in[4];
    const float* dtp    = (const float*)d_in[5];
    float* out = (float*)d_out;

    gd_scan_kernel<<<BATCH, TPB, 0, stream>>>(xicovs, dyv, cA, Cm, x0, dtp, out);
}

// Round 7
// 98.807 us; speedup vs baseline: 1.3217x; 1.0160x over previous
//
#include <hip/hip_runtime.h>

// GaussianDynamics recurrent cell as a parallel affine scan.
// x_t = S_t x_{t-1} + o_t,  S_t = I + (A - xic_t C) dt,  o_t = xic_t dy_t
// out_t = C x_{t-1} dt  (pre-update state)
//
// R7 vs R6 (100us, phases additive: VALU 45us + mem 52us):
//  - Per-wave self-staging with global_load_lds(16B): each wave DMAs its OWN
//    4KB xicov segment into its own LDS quarter. Barrier A is GONE (only an
//    intra-wave vmcnt drain) -> blocks/waves decouple, mem/compute overlap.
//  - LDS is AoS (gload_lds writes lane-linear); XOR-involution swizzle
//    pos = g ^ ((g>>3)&7) applied to the GLOBAL SOURCE address (G21) so the
//    per-thread ds_read_b128 of 4 timesteps is spread 8 lanes/4-bank group.
//  - Uniform precompute Ad = I+A*dt, nCd = -C*dt, Cd = C*dt: compose = 8 FMA.
//  - dy loaded direct per-thread (2x dwordx4, contiguous), outputs nontemporal.

constexpr int BATCH = 16384;
constexpr int TLEN  = 1000;
constexpr int TPB   = 256;
constexpr int SPT   = 4;     // TPB*SPT = 1024 >= TLEN

typedef float vfloat4 __attribute__((ext_vector_type(4)));
typedef float vfloat2 __attribute__((ext_vector_type(2)));

template <int CTRL, int ROWMASK>
__device__ __forceinline__ float dppf(float oldv, float srcv) {
    return __int_as_float(__builtin_amdgcn_update_dpp(
        __float_as_int(oldv), __float_as_int(srcv), CTRL, ROWMASK, 0xf, false));
}

__global__ __launch_bounds__(TPB, 8) void gd_scan_kernel(
    const float* __restrict__ xicovs,  // [B,T,2,2]
    const float* __restrict__ dyv,     // [B,T,2]
    const float* __restrict__ cA,      // [2,2]
    const float* __restrict__ Cm,      // [2,2]
    const float* __restrict__ x0,      // [B,2]
    const float* __restrict__ dtp,     // [1]
    float* __restrict__ out)           // [B,T,2] then [B,2]
{
    __shared__ vfloat4 s_xc[1024];        // AoS, granule = one timestep (16B)
    __shared__ float wsum[TPB / 64][6];

    const int b    = blockIdx.x;
    const int tid  = threadIdx.x;
    const int lane = tid & 63;
    const int wv   = tid >> 6;

    const int t0  = tid * SPT;
    const int t0m = (t0 <= TLEN - SPT) ? t0 : (TLEN - SPT);

    const float* rowx = xicovs + (size_t)b * TLEN * 4;

    // ---- per-wave self-staging: 4x global_load_lds(16B) into own quarter ----
    // LDS position pw = k*64+lane holds source granule gw = pw ^ ((pw>>3)&7)
    // (involution), sources clamped to granule 999 (guarded later).
#pragma unroll
    for (int k = 0; k < 4; ++k) {
        const int pw = k * 64 + lane;
        const int gw = pw ^ ((pw >> 3) & 7);
        int g = 256 * wv + gw;
        if (g > TLEN - 1) g = TLEN - 1;
        __builtin_amdgcn_global_load_lds(
            (const __attribute__((address_space(1))) void*)(rowx + (size_t)g * 4),
            (__attribute__((address_space(3))) void*)&s_xc[wv * 256 + k * 64],
            16, 0, 0);
    }

    // ---- dy: per-thread contiguous 32B (2x dwordx4), in flight with staging ----
    const vfloat4* gd4 = reinterpret_cast<const vfloat4*>(dyv + (size_t)b * TLEN * 2);
    const vfloat4 dA = gd4[(t0m >> 1)];
    const vfloat4 dB = gd4[(t0m >> 1) + 1];

    // ---- uniform precompute (scalar pipe) ----
    const float dts = dtp[0];
    const float Cd00 = Cm[0] * dts, Cd01 = Cm[1] * dts, Cd10 = Cm[2] * dts, Cd11 = Cm[3] * dts;
    const float nCd00 = -Cd00, nCd01 = -Cd01, nCd10 = -Cd10, nCd11 = -Cd11;
    const float Ad00 = 1.f + cA[0] * dts, Ad01 = cA[1] * dts;
    const float Ad10 = cA[2] * dts,       Ad11 = 1.f + cA[3] * dts;

    // ---- drain this wave's LDS-DMA (and dy) before reading LDS ----
    asm volatile("s_waitcnt vmcnt(0)" ::: "memory");

    // ---- read own 4 timesteps: swizzled ds_read_b128, conflict-minimal ----
    vfloat4 xc[SPT];
#pragma unroll
    for (int s = 0; s < SPT; ++s) {
        const int gw  = 4 * lane + s;
        const int pos = gw ^ ((gw >> 3) & 7);
        xc[s] = s_xc[wv * 256 + pos];
    }

    const float dy0s[SPT] = {dA.x, dA.z, dB.x, dB.z};
    const float dy1s[SPT] = {dA.y, dA.w, dB.y, dB.w};

    // ---- per-step affine (S,o): S = Ad + xi*nCd (8 FMA), o = xi*dy ----
    float S00s[SPT], S01s[SPT], S10s[SPT], S11s[SPT], o0s[SPT], o1s[SPT];
    float M00 = 1.f, M01 = 0.f, M10 = 0.f, M11 = 1.f, c0 = 0.f, c1 = 0.f;
#pragma unroll
    for (int s = 0; s < SPT; ++s) {
        const int t = t0 + s;
        const float xi00 = xc[s].x, xi01 = xc[s].y, xi10 = xc[s].z, xi11 = xc[s].w;
        float S00 = Ad00 + xi00 * nCd00 + xi01 * nCd10;
        float S01 = Ad01 + xi00 * nCd01 + xi01 * nCd11;
        float S10 = Ad10 + xi10 * nCd00 + xi11 * nCd10;
        float S11 = Ad11 + xi10 * nCd01 + xi11 * nCd11;
        float o0 = xi00 * dy0s[s] + xi01 * dy1s[s];
        float o1 = xi10 * dy0s[s] + xi11 * dy1s[s];
        if (t >= TLEN) { S00 = 1.f; S01 = 0.f; S10 = 0.f; S11 = 1.f; o0 = 0.f; o1 = 0.f; }
        S00s[s] = S00; S01s[s] = S01; S10s[s] = S10; S11s[s] = S11; o0s[s] = o0; o1s[s] = o1;
        const float n00 = S00 * M00 + S01 * M10;
        const float n01 = S00 * M01 + S01 * M11;
        const float n10 = S10 * M00 + S11 * M10;
        const float n11 = S10 * M01 + S11 * M11;
        const float nc0 = S00 * c0 + S01 * c1 + o0;
        const float nc1 = S10 * c0 + S11 * c1 + o1;
        M00 = n00; M01 = n01; M10 = n10; M11 = n11; c0 = nc0; c1 = nc1;
    }

    // ---- wave-level inclusive scan via DPP (VALU, no LDS pipe) ----
#define SCAN_STEP(CTRL, RM)                                        \
    do {                                                           \
        const float m00 = dppf<CTRL, RM>(1.f, M00);                \
        const float m01 = dppf<CTRL, RM>(0.f, M01);                \
        const float m10 = dppf<CTRL, RM>(0.f, M10);                \
        const float m11 = dppf<CTRL, RM>(1.f, M11);                \
        const float lc0 = dppf<CTRL, RM>(0.f, c0);                 \
        const float lc1 = dppf<CTRL, RM>(0.f, c1);                 \
        const float n00 = M00 * m00 + M01 * m10;                   \
        const float n01 = M00 * m01 + M01 * m11;                   \
        const float n10 = M10 * m00 + M11 * m10;                   \
        const float n11 = M10 * m01 + M11 * m11;                   \
        const float nc0 = M00 * lc0 + M01 * lc1 + c0;              \
        const float nc1 = M10 * lc0 + M11 * lc1 + c1;              \
        M00 = n00; M01 = n01; M10 = n10; M11 = n11;                \
        c0 = nc0; c1 = nc1;                                        \
    } while (0)

    SCAN_STEP(0x111, 0xf);  // row_shr:1
    SCAN_STEP(0x112, 0xf);  // row_shr:2
    SCAN_STEP(0x114, 0xf);  // row_shr:4
    SCAN_STEP(0x118, 0xf);  // row_shr:8
    SCAN_STEP(0x142, 0xa);  // row_bcast:15 -> rows 1,3
    SCAN_STEP(0x143, 0xc);  // row_bcast:31 -> rows 2,3
#undef SCAN_STEP

    // ---- inter-wave fixup (single remaining barrier) ----
    if (lane == 63) {
        wsum[wv][0] = M00; wsum[wv][1] = M01; wsum[wv][2] = M10; wsum[wv][3] = M11;
        wsum[wv][4] = c0;  wsum[wv][5] = c1;
    }
    __syncthreads();

    float P00 = 1.f, P01 = 0.f, P10 = 0.f, P11 = 1.f, Pc0 = 0.f, Pc1 = 0.f;
    for (int w = 0; w < wv; ++w) {
        const float w00 = wsum[w][0], w01 = wsum[w][1], w10 = wsum[w][2], w11 = wsum[w][3];
        const float wc0 = wsum[w][4], wc1 = wsum[w][5];
        const float n00 = w00 * P00 + w01 * P10;
        const float n01 = w00 * P01 + w01 * P11;
        const float n10 = w10 * P00 + w11 * P10;
        const float n11 = w10 * P01 + w11 * P11;
        const float nc0 = w00 * Pc0 + w01 * Pc1 + wc0;
        const float nc1 = w10 * Pc0 + w11 * Pc1 + wc1;
        P00 = n00; P01 = n01; P10 = n10; P11 = n11; Pc0 = nc0; Pc1 = nc1;
    }

    // ---- within-wave exclusive = inclusive of lane-1 ----
    float e00 = __shfl_up(M00, 1), e01 = __shfl_up(M01, 1);
    float e10 = __shfl_up(M10, 1), e11 = __shfl_up(M11, 1);
    float ec0 = __shfl_up(c0, 1),  ec1 = __shfl_up(c1, 1);
    if (lane == 0) { e00 = 1.f; e01 = 0.f; e10 = 0.f; e11 = 1.f; ec0 = 0.f; ec1 = 0.f; }

    // E = e o P
    const float E00 = e00 * P00 + e01 * P10;
    const float E01 = e00 * P01 + e01 * P11;
    const float E10 = e10 * P00 + e11 * P10;
    const float E11 = e10 * P01 + e11 * P11;
    const float Ec0 = e00 * Pc0 + e01 * Pc1 + ec0;
    const float Ec1 = e10 * Pc0 + e11 * Pc1 + ec1;

    // start state for this chunk: x_{t0-1} = E(x0)
    const float xa = x0[2 * b], xb = x0[2 * b + 1];
    float xq0 = E00 * xa + E01 * xb + Ec0;
    float xq1 = E10 * xa + E11 * xb + Ec1;

    // ---- replay chunk from (S,o) in registers, emit outputs (Cd folded) ----
    float o0v[SPT], o1v[SPT];
#pragma unroll
    for (int s = 0; s < SPT; ++s) {
        o0v[s] = Cd00 * xq0 + Cd01 * xq1;
        o1v[s] = Cd10 * xq0 + Cd11 * xq1;
        const float nx0 = S00s[s] * xq0 + S01s[s] * xq1 + o0s[s];
        const float nx1 = S10s[s] * xq0 + S11s[s] * xq1 + o1s[s];
        xq0 = nx0; xq1 = nx1;
    }

    float* ob = out + (size_t)b * TLEN * 2 + (size_t)t0 * 2;
    if (t0 + SPT <= TLEN) {
        vfloat4 w0 = {o0v[0], o1v[0], o0v[1], o1v[1]};
        vfloat4 w1 = {o0v[2], o1v[2], o0v[3], o1v[3]};
        __builtin_nontemporal_store(w0, reinterpret_cast<vfloat4*>(ob));
        __builtin_nontemporal_store(w1, reinterpret_cast<vfloat4*>(ob) + 1);
    } else {
        for (int s = 0; s < SPT; ++s)
            if (t0 + s < TLEN) {
                vfloat2 w = {o0v[s], o1v[s]};
                __builtin_nontemporal_store(w, reinterpret_cast<vfloat2*>(ob) + s);
            }
    }

    // thread owning the last timestep writes the final state
    if (t0 < TLEN && t0 + SPT >= TLEN) {
        float* xf = out + (size_t)BATCH * TLEN * 2 + 2 * b;
        xf[0] = xq0; xf[1] = xq1;
    }
}

extern "C" void kernel_launch(void* const* d_in, const int* in_sizes, int n_in,
                              void* d_out, int out_size, void* d_ws, size_t ws_size,
                              hipStream_t stream) {
    const float* xicovs = (const float*)d_in[0];
    const float* dyv    = (const float*)d_in[1];
    const float* cA     = (const float*)d_in[2];
    const float* Cm     = (const float*)d_in[3];
    const float* x0     = (const float*)d_in[4];
    const float* dtp    = (const float*)d_in[5];
    float* out = (float*)d_out;

    gd_scan_kernel<<<BATCH, TPB, 0, stream>>>(xicovs, dyv, cA, Cm, x0, dtp, out);
}